// Round 1
// baseline (888.118 us; speedup 1.0000x reference)
//
#include <hip/hip_runtime.h>

#define BB 8
#define PP 16
#define SS 512
#define DD 512
#define HH 8
#define NDFF 2048
#define NVOC 10000
#define SIGMA 0.1f

// ---- output offsets (in floats) ----
#define O0 0          // r4            (8,16,1,512)
#define O1 65536      // z (resampled) (8,16,1,512)
#define O2 131072     // avg_pred_after_softmax (8,1,10000)
#define O3 211072     // good_avg_pred (8,1,10000)
#define O4 291072     // max_prediction(8,1,10000)
#define O5 371072     // eps_z         (8,16,1,512)
#define O6 436608     // attn_weights  (8,16,1,512)
#define O7 502144     // K             (8,16,512,512)
#define O8 34056576   // Vs            (8,16,512,512)
#define O9 67611008   // w_new         (8,16,1)
#define O10 67611136  // I_new         (8,16,512)

// ---- workspace offsets (in floats) ----
#define WQ    0
#define WK    65536
#define WV    131072
#define WZH   196608
#define WZ    262144
#define WO1   327680
#define WH1   393216    // (128,2048) = 262144
#define WR    655360
#define WPRED 720896    // (128,10000) = 1280000
#define WMAX  2000896
#define WSUM  2001024
#define WWSQ  2001152
#define WIT   2001280   // int
#define WAMW  2001408   // int
#define WF2   2001536   // (128,512)

// out[row, col] = in[row,:] @ W[:, col] + bias[col] + 0.1*eps[row,col]
// grid (8, 4) = (b, rowgroup of 4), 512 threads (col)
__global__ __launch_bounds__(512)
void k_matvec512(const float* __restrict__ in, const float* __restrict__ W,
                 const float* __restrict__ bias, const float* __restrict__ eps,
                 float* __restrict__ out)
{
    int row0 = blockIdx.x * 16 + blockIdx.y * 4;
    int tid = threadIdx.x;
    __shared__ float rs[4][512];
#pragma unroll
    for (int p = 0; p < 4; p++) rs[p][tid] = in[(row0 + p) * 512 + tid];
    __syncthreads();
    float a0 = 0.f, a1 = 0.f, a2 = 0.f, a3 = 0.f;
#pragma unroll 4
    for (int d = 0; d < 512; d++) {
        float wv = W[d * 512 + tid];
        a0 += rs[0][d] * wv; a1 += rs[1][d] * wv;
        a2 += rs[2][d] * wv; a3 += rs[3][d] * wv;
    }
    float bv = bias[tid];
    out[(row0 + 0) * 512 + tid] = a0 + bv + SIGMA * eps[(row0 + 0) * 512 + tid];
    out[(row0 + 1) * 512 + tid] = a1 + bv + SIGMA * eps[(row0 + 1) * 512 + tid];
    out[(row0 + 2) * 512 + tid] = a2 + bv + SIGMA * eps[(row0 + 2) * 512 + tid];
    out[(row0 + 3) * 512 + tid] = a3 + bv + SIGMA * eps[(row0 + 3) * 512 + tid];
}

// fused attention per (b,p) row. grid 128, 512 threads.
__global__ __launch_bounds__(512)
void k_attn(const float* __restrict__ qws, const float* __restrict__ kws,
            const float* __restrict__ vws, const float* __restrict__ Kin,
            const float* __restrict__ Vin, const int* __restrict__ t_ptr,
            float* __restrict__ zh, float* __restrict__ out)
{
    int t = *t_ptr;
    int row = blockIdx.x;
    int tid = threadIdx.x;
    int wave = tid >> 6, lane = tid & 63;
    __shared__ float sc[8][264];

    // q fragment (8 floats per lane, head h = lane>>3)
    const float4* q4 = (const float4*)(qws + row * 512);
    float4 qa = q4[lane * 2], qb = q4[lane * 2 + 1];

    // scores: wave w handles rows s = w, w+8, ...
    for (int s = wave; s <= t; s += 8) {
        const float4* kr = (s == t) ? (const float4*)(kws + row * 512)
                                    : (const float4*)(Kin + (row * 512 + s) * 512);
        float4 a = kr[lane * 2], c = kr[lane * 2 + 1];
        float partial = qa.x * a.x + qa.y * a.y + qa.z * a.z + qa.w * a.w
                      + qb.x * c.x + qb.y * c.y + qb.z * c.z + qb.w * c.w;
#pragma unroll
        for (int m = 1; m < 8; m <<= 1) partial += __shfl_xor(partial, m, 64);
        if ((lane & 7) == 0) sc[lane >> 3][s] = partial * 0.125f;  // /sqrt(64)
    }
    __syncthreads();

    // softmax per head (wave w = head w)
    {
        int h = wave;
        float m = -3.0e38f;
        for (int s = lane; s <= t; s += 64) m = fmaxf(m, sc[h][s]);
#pragma unroll
        for (int o = 32; o; o >>= 1) m = fmaxf(m, __shfl_xor(m, o, 64));
        float sum = 0.f;
        for (int s = lane; s <= t; s += 64) { float e = __expf(sc[h][s] - m); sc[h][s] = e; sum += e; }
#pragma unroll
        for (int o = 32; o; o >>= 1) sum += __shfl_xor(sum, o, 64);
        float inv = 1.f / sum;
        for (int s = lane; s <= t; s += 64) sc[h][s] *= inv;
    }
    __syncthreads();

    // zh[row, tid] = sum_s attn[h][s] * V[row, s, tid], h = tid>>6
    {
        int h = tid >> 6;
        float acc = 0.f;
        int s = 0;
        for (; s + 4 <= t; s += 4) {
            float v0 = Vin[(row * 512 + s + 0) * 512 + tid];
            float v1 = Vin[(row * 512 + s + 1) * 512 + tid];
            float v2 = Vin[(row * 512 + s + 2) * 512 + tid];
            float v3 = Vin[(row * 512 + s + 3) * 512 + tid];
            acc += sc[h][s] * v0 + sc[h][s + 1] * v1 + sc[h][s + 2] * v2 + sc[h][s + 3] * v3;
        }
        for (; s < t; s++) acc += sc[h][s] * Vin[(row * 512 + s) * 512 + tid];
        acc += sc[h][t] * vws[row * 512 + tid];
        zh[row * 512 + tid] = acc;
    }
    // attn_weights: mean over heads, zeros past t
    {
        int s = tid;  // S == 512 == blockDim
        float a = 0.f;
        if (s <= t) {
#pragma unroll
            for (int h = 0; h < 8; h++) a += sc[h][s];
            a *= 0.125f;
        }
        out[O6 + row * 512 + s] = a;
    }
}

// layernorm: out = LN(a+b)*g + beta. grid 128, 512 threads
__global__ __launch_bounds__(512)
void k_ln(const float* __restrict__ a, const float* __restrict__ b,
          const float* __restrict__ g, const float* __restrict__ beta,
          float* __restrict__ out)
{
    __shared__ float red[8];
    int row = blockIdx.x, tid = threadIdx.x;
    float x = a[row * 512 + tid] + b[row * 512 + tid];
    float s = x;
#pragma unroll
    for (int o = 32; o; o >>= 1) s += __shfl_xor(s, o, 64);
    if ((tid & 63) == 0) red[tid >> 6] = s;
    __syncthreads();
    float tot = 0.f;
#pragma unroll
    for (int i = 0; i < 8; i++) tot += red[i];
    float mu = tot * (1.f / 512.f);
    float dx = x - mu;
    float s2 = dx * dx;
#pragma unroll
    for (int o = 32; o; o >>= 1) s2 += __shfl_xor(s2, o, 64);
    __syncthreads();
    if ((tid & 63) == 0) red[tid >> 6] = s2;
    __syncthreads();
    float tot2 = 0.f;
#pragma unroll
    for (int i = 0; i < 8; i++) tot2 += red[i];
    float var = tot2 * (1.f / 512.f);
    out[row * 512 + tid] = dx * rsqrtf(var + 1e-6f) * g[tid] + beta[tid];
}

// h1 = relu(out1 @ W1 + b1). grid (8,4,4) = (b, rowgroup4, colchunk512)
__global__ __launch_bounds__(512)
void k_ffn1(const float* __restrict__ in, const float* __restrict__ W1,
            const float* __restrict__ b1, float* __restrict__ h1)
{
    int row0 = blockIdx.x * 16 + blockIdx.y * 4;
    int col = blockIdx.z * 512 + threadIdx.x;
    int tid = threadIdx.x;
    __shared__ float rs[4][512];
#pragma unroll
    for (int p = 0; p < 4; p++) rs[p][tid] = in[(row0 + p) * 512 + tid];
    __syncthreads();
    float a0 = 0.f, a1 = 0.f, a2 = 0.f, a3 = 0.f;
#pragma unroll 4
    for (int d = 0; d < 512; d++) {
        float wv = W1[d * NDFF + col];
        a0 += rs[0][d] * wv; a1 += rs[1][d] * wv;
        a2 += rs[2][d] * wv; a3 += rs[3][d] * wv;
    }
    float bv = b1[col];
    h1[(row0 + 0) * NDFF + col] = fmaxf(a0 + bv, 0.f);
    h1[(row0 + 1) * NDFF + col] = fmaxf(a1 + bv, 0.f);
    h1[(row0 + 2) * NDFF + col] = fmaxf(a2 + bv, 0.f);
    h1[(row0 + 3) * NDFF + col] = fmaxf(a3 + bv, 0.f);
}

// f2 = h1 @ W2 + b2. grid (8,4), K=2048 chunked by 512
__global__ __launch_bounds__(512)
void k_ffn2(const float* __restrict__ h1, const float* __restrict__ W2,
            const float* __restrict__ b2, float* __restrict__ f2)
{
    int row0 = blockIdx.x * 16 + blockIdx.y * 4;
    int tid = threadIdx.x;
    __shared__ float hs[4][512];
    float a0 = 0.f, a1 = 0.f, a2 = 0.f, a3 = 0.f;
    for (int kc = 0; kc < 4; kc++) {
        __syncthreads();
#pragma unroll
        for (int p = 0; p < 4; p++) hs[p][tid] = h1[(row0 + p) * NDFF + kc * 512 + tid];
        __syncthreads();
#pragma unroll 4
        for (int d = 0; d < 512; d++) {
            float wv = W2[(kc * 512 + d) * 512 + tid];
            a0 += hs[0][d] * wv; a1 += hs[1][d] * wv;
            a2 += hs[2][d] * wv; a3 += hs[3][d] * wv;
        }
    }
    float bv = b2[tid];
    f2[(row0 + 0) * 512 + tid] = a0 + bv;
    f2[(row0 + 1) * 512 + tid] = a1 + bv;
    f2[(row0 + 2) * 512 + tid] = a2 + bv;
    f2[(row0 + 3) * 512 + tid] = a3 + bv;
}

// pred = r_ @ Wout + bout. grid (20, 4) = (colchunk512, rowgroup32)
__global__ __launch_bounds__(512)
void k_pred(const float* __restrict__ r_, const float* __restrict__ Wout,
            const float* __restrict__ bout, float* __restrict__ pred)
{
    int col = blockIdx.x * 512 + threadIdx.x;
    bool ok = col < NVOC;
    int row0 = blockIdx.y * 32;
    __shared__ float rs[32][256];
    float acc[32];
#pragma unroll
    for (int p = 0; p < 32; p++) acc[p] = 0.f;
    for (int kc = 0; kc < 2; kc++) {
        __syncthreads();
        for (int i = threadIdx.x; i < 32 * 256; i += 512) {
            int p = i >> 8, d = i & 255;
            rs[p][d] = r_[(row0 + p) * 512 + kc * 256 + d];
        }
        __syncthreads();
        if (ok) {
#pragma unroll 2
            for (int d = 0; d < 256; d++) {
                float wv = Wout[(kc * 256 + d) * NVOC + col];
#pragma unroll
                for (int p = 0; p < 32; p++) acc[p] += rs[p][d] * wv;
            }
        }
    }
    if (ok) {
        float bv = bout[col];
#pragma unroll
        for (int p = 0; p < 32; p++) pred[(row0 + p) * NVOC + col] = acc[p] + bv;
    }
}

// per-row softmax stats + w_sq. grid 128, 512 threads
__global__ __launch_bounds__(512)
void k_soft(const float* __restrict__ pred, const int* __restrict__ x,
            float* __restrict__ rowmax, float* __restrict__ rowsum,
            float* __restrict__ wsq, float* __restrict__ out)
{
    __shared__ float red[8];
    int row = blockIdx.x, tid = threadIdx.x;
    const float* pr = pred + row * NVOC;
    float m = -3.0e38f;
    for (int v = tid; v < NVOC; v += 512) m = fmaxf(m, pr[v]);
#pragma unroll
    for (int o = 32; o; o >>= 1) m = fmaxf(m, __shfl_xor(m, o, 64));
    if ((tid & 63) == 0) red[tid >> 6] = m;
    __syncthreads();
#pragma unroll
    for (int i = 0; i < 8; i++) m = fmaxf(m, red[i]);
    __syncthreads();
    float s = 0.f;
    for (int v = tid; v < NVOC; v += 512) s += __expf(pr[v] - m);
#pragma unroll
    for (int o = 32; o; o >>= 1) s += __shfl_xor(s, o, 64);
    if ((tid & 63) == 0) red[tid >> 6] = s;
    __syncthreads();
    if (tid == 0) {
        float tot = 0.f;
#pragma unroll
        for (int i = 0; i < 8; i++) tot += red[i];
        rowmax[row] = m; rowsum[row] = tot;
        int b = row >> 4;
        float w = __expf(pr[x[b]] - m) / tot;
        wsq[row] = w;
        out[O9 + row] = w;
    }
}

// gumbel argmax i_t + argmax_w. 1 block, 128 threads
__global__ __launch_bounds__(128)
void k_sample(const float* __restrict__ wsq, const float* __restrict__ gumbel,
              int* __restrict__ it, int* __restrict__ amw)
{
    int tid = threadIdx.x;
    int b = tid >> 4, p = tid & 15;
    float best = -3.0e38f; int bi = 0;
#pragma unroll
    for (int pp = 0; pp < 16; pp++) {
        float v = logf(wsq[b * 16 + pp] + 1e-10f) + gumbel[tid * 16 + pp];
        if (v > best) { best = v; bi = pp; }
    }
    it[tid] = bi;
    if (p == 0) {
        float bw = -3.0e38f; int bj = 0;
#pragma unroll
        for (int pp = 0; pp < 16; pp++) {
            float wv = wsq[b * 16 + pp];
            if (wv > bw) { bw = wv; bj = pp; }
        }
        amw[b] = bj;
    }
}

// vocab-wide outputs. grid (20, 8) = (colchunk512, b)
__global__ __launch_bounds__(512)
void k_vocab(const float* __restrict__ pred, const float* __restrict__ rowmax,
             const float* __restrict__ rowsum, const int* __restrict__ amw,
             float* __restrict__ out)
{
    int v = blockIdx.x * 512 + threadIdx.x;
    if (v >= NVOC) return;
    int b = blockIdx.y;
    float ga = 0.f, as = 0.f;
#pragma unroll
    for (int p = 0; p < 16; p++) {
        int rr = b * 16 + p;
        float pv = pred[rr * NVOC + v];
        ga += pv;
        as += __expf(pv - rowmax[rr]) * (1.f / rowsum[rr]);
    }
    out[O3 + b * NVOC + v] = ga * (1.f / 16.f);
    out[O2 + b * NVOC + v] = as * (1.f / 16.f);
    out[O4 + b * NVOC + v] = pred[(b * 16 + amw[b]) * NVOC + v];
}

// K / Vs resample. grid 65536 (= row index (b,p,s)), 128 threads (float4)
// K_out[b,p,s<=t] = K_set[b, i_t[b,p], s];  Vs_out[b,p,s<=t] = K_set[b, i_t[b,i_t[b,p]], s]
__global__ __launch_bounds__(128)
void k_resample(const float* __restrict__ Kin, const float* __restrict__ kws,
                const int* __restrict__ it, const int* __restrict__ t_ptr,
                float* __restrict__ out)
{
    int t = *t_ptr;
    int rowidx = blockIdx.x;
    int s = rowidx & 511;
    int bp = rowidx >> 9;
    int b = bp >> 4;
    int tid = threadIdx.x;
    float4 vK, vV;
    if (s > t) {
        vK = ((const float4*)Kin)[rowidx * 128 + tid];
        vV = vK;
    } else {
        int ip = it[bp];
        int ip2 = it[b * 16 + ip];
        if (s == t) {
            vK = ((const float4*)kws)[(b * 16 + ip) * 128 + tid];
            vV = ((const float4*)kws)[(b * 16 + ip2) * 128 + tid];
        } else {
            vK = ((const float4*)Kin)[((b * 16 + ip) * 512 + s) * 128 + tid];
            vV = ((const float4*)Kin)[((b * 16 + ip2) * 512 + s) * 128 + tid];
        }
    }
    ((float4*)(out + O7))[rowidx * 128 + tid] = vK;
    ((float4*)(out + O8))[rowidx * 128 + tid] = vV;
}

// small copies: r4, eps_z, z-resample, I_new. grid 256, 256 threads
__global__ __launch_bounds__(256)
void k_misc(const float* __restrict__ r, const float* __restrict__ epsz,
            const float* __restrict__ zws, const int* __restrict__ Iin,
            const int* __restrict__ it, const int* __restrict__ t_ptr,
            float* __restrict__ out)
{
    int t = *t_ptr;
    int idx = blockIdx.x * 256 + threadIdx.x;  // 0..65535
    out[O0 + idx] = r[idx];
    out[O5 + idx] = epsz[idx];
    int row = idx >> 9, d = idx & 511;
    int b = row >> 4;
    int ip = it[row];
    out[O1 + idx] = zws[((b * 16 + ip) << 9) + d];
    int s = d;
    float iv;
    if (s < t)       iv = (float)Iin[((b * 16 + ip) << 9) + s];
    else if (s == t) iv = (float)ip;
    else             iv = (float)Iin[idx];
    out[O10 + idx] = iv;
}

extern "C" void kernel_launch(void* const* d_in, const int* in_sizes, int n_in,
                              void* d_out, int out_size, void* d_ws, size_t ws_size,
                              hipStream_t stream) {
    const float* r      = (const float*)d_in[0];
    const int*   x      = (const int*)d_in[1];
    const float* Kin    = (const float*)d_in[2];
    const float* Vin    = (const float*)d_in[3];
    // d_in[4] = w : unused by reference
    const int*   Iin    = (const int*)d_in[5];
    const int*   t_ptr  = (const int*)d_in[6];
    const float* eps_q  = (const float*)d_in[7];
    const float* eps_k  = (const float*)d_in[8];
    const float* eps_v  = (const float*)d_in[9];
    const float* eps_z  = (const float*)d_in[10];
    const float* gumbel = (const float*)d_in[11];
    const float* Wq = (const float*)d_in[12]; const float* bq = (const float*)d_in[13];
    const float* Wk = (const float*)d_in[14]; const float* bk = (const float*)d_in[15];
    const float* Wv = (const float*)d_in[16]; const float* bv = (const float*)d_in[17];
    const float* Wo = (const float*)d_in[18]; const float* bo = (const float*)d_in[19];
    const float* ln1_g = (const float*)d_in[20]; const float* ln1_b = (const float*)d_in[21];
    const float* ln3_g = (const float*)d_in[22]; const float* ln3_b = (const float*)d_in[23];
    const float* W1 = (const float*)d_in[24]; const float* b1 = (const float*)d_in[25];
    const float* W2 = (const float*)d_in[26]; const float* b2 = (const float*)d_in[27];
    const float* Wout = (const float*)d_in[28]; const float* bout = (const float*)d_in[29];

    float* ws  = (float*)d_ws;
    float* q   = ws + WQ;
    float* kv  = ws + WK;
    float* vv  = ws + WV;
    float* zh  = ws + WZH;
    float* zp  = ws + WZ;
    float* o1  = ws + WO1;
    float* h1  = ws + WH1;
    float* rr  = ws + WR;
    float* pr  = ws + WPRED;
    float* rmx = ws + WMAX;
    float* rsm = ws + WSUM;
    float* wsq = ws + WWSQ;
    int*   itw = (int*)(ws + WIT);
    int*   amw = (int*)(ws + WAMW);
    float* f2  = ws + WF2;
    float* outp = (float*)d_out;

    dim3 g84(8, 4);
    k_matvec512<<<g84, 512, 0, stream>>>(r, Wq, bq, eps_q, q);
    k_matvec512<<<g84, 512, 0, stream>>>(r, Wk, bk, eps_k, kv);
    k_matvec512<<<g84, 512, 0, stream>>>(r, Wv, bv, eps_v, vv);
    k_attn<<<128, 512, 0, stream>>>(q, kv, vv, Kin, Vin, t_ptr, zh, outp);
    k_matvec512<<<g84, 512, 0, stream>>>(zh, Wo, bo, eps_z, zp);
    k_ln<<<128, 512, 0, stream>>>(zp, r, ln1_g, ln1_b, o1);
    k_ffn1<<<dim3(8, 4, 4), 512, 0, stream>>>(o1, W1, b1, h1);
    k_ffn2<<<g84, 512, 0, stream>>>(h1, W2, b2, f2);
    k_ln<<<128, 512, 0, stream>>>(f2, o1, ln3_g, ln3_b, rr);
    k_pred<<<dim3(20, 4), 512, 0, stream>>>(rr, Wout, bout, pr);
    k_soft<<<128, 512, 0, stream>>>(pr, x, rmx, rsm, wsq, outp);
    k_sample<<<1, 128, 0, stream>>>(wsq, gumbel, itw, amw);
    k_vocab<<<dim3(20, 8), 512, 0, stream>>>(pr, rmx, rsm, amw, outp);
    k_resample<<<65536, 128, 0, stream>>>(Kin, kv, itw, t_ptr, outp);
    k_misc<<<256, 256, 0, stream>>>(r, eps_z, zp, Iin, itw, t_ptr, outp);
}

// Round 2
// 317.462 us; speedup vs baseline: 2.7976x; 2.7976x over previous
//
#include <hip/hip_runtime.h>

#define NDFF 2048
#define NVOC 10000
#define SIGMA 0.1f

// ---- output offsets (floats) ----
#define O0 0
#define O1 65536
#define O2 131072
#define O3 211072
#define O4 291072
#define O5 371072
#define O6 436608
#define O7 502144
#define O8 34056576
#define O9 67611008
#define O10 67611136

// ---- workspace offsets (floats) ----
#define WQ    0
#define WK    65536
#define WV    131072
#define WZ    196608
#define WO1   262144
#define WH1   327680
#define WR    589824
#define WPRED 655360
#define WMAX  1935360
#define WSUM  1935488
#define WWSQ  1935616
#define WIT   1935744
#define WAMW  1935872
#define WF2P  1936000   // 4 x 128 x 512
#define WSC   2198144   // 128 x 8 x 512 scores/attn
#define WZP   2722432   // 4 x 128 x 512 pv partials

// ===== fused QKV projection: out = r @ W + b + SIGMA*eps =====
// grid (4 coltiles of 128, 16 rowgroups of 8, 3 matrices), 512 thr
__global__ __launch_bounds__(512)
void k_qkv(const float* __restrict__ r,
           const float* __restrict__ Wq, const float* __restrict__ bq, const float* __restrict__ eq, float* __restrict__ oq,
           const float* __restrict__ Wk, const float* __restrict__ bk, const float* __restrict__ ek, float* __restrict__ ok,
           const float* __restrict__ Wv, const float* __restrict__ bv, const float* __restrict__ ev, float* __restrict__ ov)
{
    const float *W, *bias, *eps; float* out;
    if (blockIdx.z == 0)      { W = Wq; bias = bq; eps = eq; out = oq; }
    else if (blockIdx.z == 1) { W = Wk; bias = bk; eps = ek; out = ok; }
    else                      { W = Wv; bias = bv; eps = ev; out = ov; }
    int tid = threadIdx.x;
    int col = tid & 127, kq = tid >> 7;
    int colg = blockIdx.x * 128 + col;
    int row0 = blockIdx.y * 8;
    __shared__ float rs[8][512];
#pragma unroll
    for (int p = 0; p < 8; p++) rs[p][tid & 511] = r[(row0 + p) * 512 + tid];
    __syncthreads();
    float acc[8] = {0,0,0,0,0,0,0,0};
    const float* Wp = W + (kq * 128) * 512 + colg;
#pragma unroll 8
    for (int d = 0; d < 128; d++) {
        float wv = Wp[d * 512];
#pragma unroll
        for (int p = 0; p < 8; p++) acc[p] += rs[p][kq * 128 + d] * wv;
    }
    __syncthreads();
    float (*part)[8][128] = (float(*)[8][128])rs;
#pragma unroll
    for (int p = 0; p < 8; p++) part[kq][p][col] = acc[p];
    __syncthreads();
#pragma unroll
    for (int j = 0; j < 2; j++) {
        int idx = tid + j * 512;
        int p = idx >> 7, c = idx & 127;
        int cg = blockIdx.x * 128 + c;
        float v = part[0][p][c] + part[1][p][c] + part[2][p][c] + part[3][p][c]
                + bias[cg] + SIGMA * eps[(row0 + p) * 512 + cg];
        out[(row0 + p) * 512 + cg] = v;
    }
}

// ===== attention scores: grid (128 bp, 4 schunk), 512 thr =====
__global__ __launch_bounds__(512)
void k_score(const float* __restrict__ qws, const float* __restrict__ kws,
             const float* __restrict__ Kin, const int* __restrict__ t_ptr,
             float* __restrict__ scw)
{
    int t = *t_ptr;
    int bp = blockIdx.x;
    int len = (t + 4) >> 2;
    int lo = blockIdx.y * len;
    int hi = min(lo + len, t + 1);
    int tid = threadIdx.x;
    int wave = tid >> 6, lane = tid & 63;
    const float4* q4 = (const float4*)(qws + bp * 512);
    float4 qa = q4[lane * 2], qb = q4[lane * 2 + 1];
    for (int s = lo + wave; s < hi; s += 8) {
        const float4* kr = (s == t) ? (const float4*)(kws + bp * 512)
                                    : (const float4*)(Kin + (bp * 512 + s) * 512);
        float4 a = kr[lane * 2], c = kr[lane * 2 + 1];
        float partial = qa.x * a.x + qa.y * a.y + qa.z * a.z + qa.w * a.w
                      + qb.x * c.x + qb.y * c.y + qb.z * c.z + qb.w * c.w;
#pragma unroll
        for (int m = 1; m < 8; m <<= 1) partial += __shfl_xor(partial, m, 64);
        if ((lane & 7) == 0) scw[(bp * 8 + (lane >> 3)) * 512 + s] = partial * 0.125f;
    }
}

// ===== softmax per (bp, head) + attn_weights output. grid 128, 512 thr =====
__global__ __launch_bounds__(512)
void k_smax(float* __restrict__ scw, const int* __restrict__ t_ptr,
            float* __restrict__ out)
{
    int t = *t_ptr;
    int bp = blockIdx.x;
    int tid = threadIdx.x;
    int h = tid >> 6, lane = tid & 63;
    float* sp = scw + (bp * 8 + h) * 512;
    float m = -3.0e38f;
    for (int s = lane; s <= t; s += 64) m = fmaxf(m, sp[s]);
#pragma unroll
    for (int o = 32; o; o >>= 1) m = fmaxf(m, __shfl_xor(m, o, 64));
    float sum = 0.f;
    for (int s = lane; s <= t; s += 64) { float e = __expf(sp[s] - m); sp[s] = e; sum += e; }
#pragma unroll
    for (int o = 32; o; o >>= 1) sum += __shfl_xor(sum, o, 64);
    float inv = 1.f / sum;
    for (int s = lane; s <= t; s += 64) sp[s] *= inv;
    __syncthreads();
    int s = tid;
    float a = 0.f;
    if (s <= t) {
#pragma unroll
        for (int hh = 0; hh < 8; hh++) a += scw[(bp * 8 + hh) * 512 + s];
        a *= 0.125f;
    }
    out[O6 + bp * 512 + s] = a;
}

// ===== PV partial: grid (128 bp, 4 schunk), 512 thr =====
__global__ __launch_bounds__(512)
void k_pv(const float* __restrict__ scw, const float* __restrict__ vws,
          const float* __restrict__ Vin, const int* __restrict__ t_ptr,
          float* __restrict__ zpart)
{
    int t = *t_ptr;
    int bp = blockIdx.x;
    int sc = blockIdx.y;
    int len = (t + 4) >> 2;
    int lo = sc * len;
    int hi = min(lo + len, t + 1);
    int tid = threadIdx.x;
    int h = tid >> 6;
    __shared__ float sa[8][136];
    for (int idx = tid; idx < 8 * len; idx += 512) {
        int hh = idx / len, j = idx - hh * len;
        int s = lo + j;
        sa[hh][j] = (s <= t) ? scw[(bp * 8 + hh) * 512 + s] : 0.f;
    }
    __syncthreads();
    float acc = 0.f;
    int hv = min(hi, t);   // rows strictly below t
    int s = lo;
    for (; s + 4 <= hv; s += 4) {
        float v0 = Vin[(bp * 512 + s + 0) * 512 + tid];
        float v1 = Vin[(bp * 512 + s + 1) * 512 + tid];
        float v2 = Vin[(bp * 512 + s + 2) * 512 + tid];
        float v3 = Vin[(bp * 512 + s + 3) * 512 + tid];
        acc += sa[h][s - lo] * v0 + sa[h][s + 1 - lo] * v1
             + sa[h][s + 2 - lo] * v2 + sa[h][s + 3 - lo] * v3;
    }
    for (; s < hv; s++) acc += sa[h][s - lo] * Vin[(bp * 512 + s) * 512 + tid];
    if (t >= lo && t < hi) acc += sa[h][t - lo] * vws[bp * 512 + tid];
    zpart[sc * 65536 + bp * 512 + tid] = acc;
}

// ===== z projection: zh = sum(zpart), zp = zh @ Wo + bo + SIGMA*eps_z =====
// grid (4 coltiles, 16 rowgroups of 8), 512 thr
__global__ __launch_bounds__(512)
void k_zproj(const float* __restrict__ zpart, const float* __restrict__ Wo,
             const float* __restrict__ bo, const float* __restrict__ epsz,
             float* __restrict__ out)
{
    int tid = threadIdx.x;
    int col = tid & 127, kq = tid >> 7;
    int colg = blockIdx.x * 128 + col;
    int row0 = blockIdx.y * 8;
    __shared__ float rs[8][512];
#pragma unroll
    for (int p = 0; p < 8; p++) {
        int idx = (row0 + p) * 512 + tid;
        rs[p][tid] = zpart[idx] + zpart[65536 + idx] + zpart[131072 + idx] + zpart[196608 + idx];
    }
    __syncthreads();
    float acc[8] = {0,0,0,0,0,0,0,0};
    const float* Wp = Wo + (kq * 128) * 512 + colg;
#pragma unroll 8
    for (int d = 0; d < 128; d++) {
        float wv = Wp[d * 512];
#pragma unroll
        for (int p = 0; p < 8; p++) acc[p] += rs[p][kq * 128 + d] * wv;
    }
    __syncthreads();
    float (*part)[8][128] = (float(*)[8][128])rs;
#pragma unroll
    for (int p = 0; p < 8; p++) part[kq][p][col] = acc[p];
    __syncthreads();
#pragma unroll
    for (int j = 0; j < 2; j++) {
        int idx = tid + j * 512;
        int p = idx >> 7, c = idx & 127;
        int cg = blockIdx.x * 128 + c;
        out[(row0 + p) * 512 + cg] = part[0][p][c] + part[1][p][c] + part[2][p][c] + part[3][p][c]
                                   + bo[cg] + SIGMA * epsz[(row0 + p) * 512 + cg];
    }
}

// ===== layernorm: out = LN(a+b)*g + beta. grid 128, 512 thr =====
__global__ __launch_bounds__(512)
void k_ln(const float* __restrict__ a, const float* __restrict__ b,
          const float* __restrict__ g, const float* __restrict__ beta,
          float* __restrict__ out)
{
    __shared__ float red[8];
    int row = blockIdx.x, tid = threadIdx.x;
    float x = a[row * 512 + tid] + b[row * 512 + tid];
    float s = x;
#pragma unroll
    for (int o = 32; o; o >>= 1) s += __shfl_xor(s, o, 64);
    if ((tid & 63) == 0) red[tid >> 6] = s;
    __syncthreads();
    float tot = 0.f;
#pragma unroll
    for (int i = 0; i < 8; i++) tot += red[i];
    float mu = tot * (1.f / 512.f);
    float dx = x - mu;
    float s2 = dx * dx;
#pragma unroll
    for (int o = 32; o; o >>= 1) s2 += __shfl_xor(s2, o, 64);
    __syncthreads();
    if ((tid & 63) == 0) red[tid >> 6] = s2;
    __syncthreads();
    float tot2 = 0.f;
#pragma unroll
    for (int i = 0; i < 8; i++) tot2 += red[i];
    float var = tot2 * (1.f / 512.f);
    out[row * 512 + tid] = dx * rsqrtf(var + 1e-6f) * g[tid] + beta[tid];
}

// ===== ln3 with ffn2-partial reduction: out = LN(sum(f2p)+b2 + o1) =====
__global__ __launch_bounds__(512)
void k_ln_sum4(const float* __restrict__ f2p, const float* __restrict__ b2,
               const float* __restrict__ o1, const float* __restrict__ g,
               const float* __restrict__ beta, float* __restrict__ out)
{
    __shared__ float red[8];
    int row = blockIdx.x, tid = threadIdx.x;
    int idx = row * 512 + tid;
    float x = f2p[idx] + f2p[65536 + idx] + f2p[131072 + idx] + f2p[196608 + idx]
            + b2[tid] + o1[idx];
    float s = x;
#pragma unroll
    for (int o = 32; o; o >>= 1) s += __shfl_xor(s, o, 64);
    if ((tid & 63) == 0) red[tid >> 6] = s;
    __syncthreads();
    float tot = 0.f;
#pragma unroll
    for (int i = 0; i < 8; i++) tot += red[i];
    float mu = tot * (1.f / 512.f);
    float dx = x - mu;
    float s2 = dx * dx;
#pragma unroll
    for (int o = 32; o; o >>= 1) s2 += __shfl_xor(s2, o, 64);
    __syncthreads();
    if ((tid & 63) == 0) red[tid >> 6] = s2;
    __syncthreads();
    float tot2 = 0.f;
#pragma unroll
    for (int i = 0; i < 8; i++) tot2 += red[i];
    float var = tot2 * (1.f / 512.f);
    out[idx] = dx * rsqrtf(var + 1e-6f) * g[tid] + beta[tid];
}

// ===== ffn1: h1 = relu(o1 @ W1 + b1). grid (16 coltiles, 8 rowgroups of 16), 512 thr =====
__global__ __launch_bounds__(512)
void k_ffn1(const float* __restrict__ in, const float* __restrict__ W1,
            const float* __restrict__ b1, float* __restrict__ h1)
{
    int tid = threadIdx.x;
    int col = tid & 127, kq = tid >> 7;
    int colg = blockIdx.x * 128 + col;
    int row0 = blockIdx.y * 16;
    __shared__ float rs[16][512];
#pragma unroll
    for (int j = 0; j < 16; j++) {
        int idx = tid + j * 512;
        rs[idx >> 9][idx & 511] = in[(row0 + (idx >> 9)) * 512 + (idx & 511)];
    }
    __syncthreads();
    float acc[16];
#pragma unroll
    for (int p = 0; p < 16; p++) acc[p] = 0.f;
    const float* Wp = W1 + (kq * 128) * NDFF + colg;
#pragma unroll 8
    for (int d = 0; d < 128; d++) {
        float wv = Wp[d * NDFF];
#pragma unroll
        for (int p = 0; p < 16; p++) acc[p] += rs[p][kq * 128 + d] * wv;
    }
    __syncthreads();
    float (*part)[16][128] = (float(*)[16][128])rs;
#pragma unroll
    for (int p = 0; p < 16; p++) part[kq][p][col] = acc[p];
    __syncthreads();
#pragma unroll
    for (int j = 0; j < 4; j++) {
        int idx = tid + j * 512;
        int p = idx >> 7, c = idx & 127;
        int cg = blockIdx.x * 128 + c;
        float v = part[0][p][c] + part[1][p][c] + part[2][p][c] + part[3][p][c] + b1[cg];
        h1[(row0 + p) * NDFF + cg] = fmaxf(v, 0.f);
    }
}

// ===== ffn2 partials: grid (4 coltiles, 8 rowgroups of 16, 4 ksect of 512), 512 thr =====
__global__ __launch_bounds__(512)
void k_ffn2p(const float* __restrict__ h1, const float* __restrict__ W2,
             float* __restrict__ f2p)
{
    int tid = threadIdx.x;
    int col = tid & 127, kq = tid >> 7;
    int colg = blockIdx.x * 128 + col;
    int row0 = blockIdx.y * 16;
    int ks = blockIdx.z;
    __shared__ float rs[16][512];
#pragma unroll
    for (int j = 0; j < 16; j++) {
        int idx = tid + j * 512;
        rs[idx >> 9][idx & 511] = h1[(row0 + (idx >> 9)) * NDFF + ks * 512 + (idx & 511)];
    }
    __syncthreads();
    float acc[16];
#pragma unroll
    for (int p = 0; p < 16; p++) acc[p] = 0.f;
    const float* Wp = W2 + (ks * 512 + kq * 128) * 512 + colg;
#pragma unroll 8
    for (int d = 0; d < 128; d++) {
        float wv = Wp[d * 512];
#pragma unroll
        for (int p = 0; p < 16; p++) acc[p] += rs[p][kq * 128 + d] * wv;
    }
    __syncthreads();
    float (*part)[16][128] = (float(*)[16][128])rs;
#pragma unroll
    for (int p = 0; p < 16; p++) part[kq][p][col] = acc[p];
    __syncthreads();
#pragma unroll
    for (int j = 0; j < 4; j++) {
        int idx = tid + j * 512;
        int p = idx >> 7, c = idx & 127;
        int cg = blockIdx.x * 128 + c;
        f2p[ks * 65536 + (row0 + p) * 512 + cg] =
            part[0][p][c] + part[1][p][c] + part[2][p][c] + part[3][p][c];
    }
}

// ===== pred = r_ @ Wout + bout. grid (40 coltiles of 256, 4 rowgroups of 32), 512 thr =====
__global__ __launch_bounds__(512)
void k_pred(const float* __restrict__ r_, const float* __restrict__ Wout,
            const float* __restrict__ bout, float* __restrict__ pred)
{
    int tid = threadIdx.x;
    int col = tid & 255, kh = tid >> 8;
    int colg = blockIdx.x * 256 + col;
    int colL = min(colg, NVOC - 1);
    int row0 = blockIdx.y * 32;
    __shared__ float rs[32][256];
    float acc[32];
#pragma unroll
    for (int p = 0; p < 32; p++) acc[p] = 0.f;
    for (int kc = 0; kc < 2; kc++) {
        __syncthreads();
#pragma unroll
        for (int j = 0; j < 16; j++) {
            int idx = tid + j * 512;
            rs[idx >> 8][idx & 255] = r_[(row0 + (idx >> 8)) * 512 + kc * 256 + (idx & 255)];
        }
        __syncthreads();
        const float* Wp = Wout + (kc * 256 + kh * 128) * NVOC + colL;
#pragma unroll 4
        for (int d = 0; d < 128; d++) {
            float wv = Wp[d * NVOC];
#pragma unroll
            for (int p = 0; p < 32; p++) acc[p] += rs[p][kh * 128 + d] * wv;
        }
    }
    __syncthreads();
    float (*part)[256] = (float(*)[256])rs;   // 32x256 = kh1 partials
    if (kh == 1) {
#pragma unroll
        for (int p = 0; p < 32; p++) part[p][col] = acc[p];
    }
    __syncthreads();
    if (kh == 0 && colg < NVOC) {
        float bv = bout[colg];
#pragma unroll
        for (int p = 0; p < 32; p++)
            pred[(row0 + p) * NVOC + colg] = acc[p] + part[p][col] + bv;
    }
}

// ===== per-row softmax stats + w_sq. grid 128, 512 thr =====
__global__ __launch_bounds__(512)
void k_soft(const float* __restrict__ pred, const int* __restrict__ x,
            float* __restrict__ rowmax, float* __restrict__ rowsum,
            float* __restrict__ wsq, float* __restrict__ out)
{
    __shared__ float red[8];
    int row = blockIdx.x, tid = threadIdx.x;
    const float* pr = pred + row * NVOC;
    float m = -3.0e38f;
    for (int v = tid; v < NVOC; v += 512) m = fmaxf(m, pr[v]);
#pragma unroll
    for (int o = 32; o; o >>= 1) m = fmaxf(m, __shfl_xor(m, o, 64));
    if ((tid & 63) == 0) red[tid >> 6] = m;
    __syncthreads();
#pragma unroll
    for (int i = 0; i < 8; i++) m = fmaxf(m, red[i]);
    __syncthreads();
    float s = 0.f;
    for (int v = tid; v < NVOC; v += 512) s += __expf(pr[v] - m);
#pragma unroll
    for (int o = 32; o; o >>= 1) s += __shfl_xor(s, o, 64);
    if ((tid & 63) == 0) red[tid >> 6] = s;
    __syncthreads();
    if (tid == 0) {
        float tot = 0.f;
#pragma unroll
        for (int i = 0; i < 8; i++) tot += red[i];
        rowmax[row] = m; rowsum[row] = tot;
        int b = row >> 4;
        float w = __expf(pr[x[b]] - m) / tot;
        wsq[row] = w;
        out[O9 + row] = w;
    }
}

// ===== gumbel argmax + argmax_w. 1 block, 128 thr =====
__global__ __launch_bounds__(128)
void k_sample(const float* __restrict__ wsq, const float* __restrict__ gumbel,
              int* __restrict__ it, int* __restrict__ amw)
{
    int tid = threadIdx.x;
    int b = tid >> 4, p = tid & 15;
    float best = -3.0e38f; int bi = 0;
#pragma unroll
    for (int pp = 0; pp < 16; pp++) {
        float v = logf(wsq[b * 16 + pp] + 1e-10f) + gumbel[tid * 16 + pp];
        if (v > best) { best = v; bi = pp; }
    }
    it[tid] = bi;
    if (p == 0) {
        float bw = -3.0e38f; int bj = 0;
#pragma unroll
        for (int pp = 0; pp < 16; pp++) {
            float wv = wsq[b * 16 + pp];
            if (wv > bw) { bw = wv; bj = pp; }
        }
        amw[b] = bj;
    }
}

// ===== vocab outputs. grid (20, 8), 512 thr =====
__global__ __launch_bounds__(512)
void k_vocab(const float* __restrict__ pred, const float* __restrict__ rowmax,
             const float* __restrict__ rowsum, const int* __restrict__ amw,
             float* __restrict__ out)
{
    int v = blockIdx.x * 512 + threadIdx.x;
    if (v >= NVOC) return;
    int b = blockIdx.y;
    float ga = 0.f, as = 0.f;
#pragma unroll
    for (int p = 0; p < 16; p++) {
        int rr = b * 16 + p;
        float pv = pred[rr * NVOC + v];
        ga += pv;
        as += __expf(pv - rowmax[rr]) * (1.f / rowsum[rr]);
    }
    out[O3 + b * NVOC + v] = ga * (1.f / 16.f);
    out[O2 + b * NVOC + v] = as * (1.f / 16.f);
    out[O4 + b * NVOC + v] = pred[(b * 16 + amw[b]) * NVOC + v];
}

// ===== K / Vs resample. grid 65536, 128 thr =====
__global__ __launch_bounds__(128)
void k_resample(const float* __restrict__ Kin, const float* __restrict__ kws,
                const int* __restrict__ it, const int* __restrict__ t_ptr,
                float* __restrict__ out)
{
    int t = *t_ptr;
    int rowidx = blockIdx.x;
    int s = rowidx & 511;
    int bp = rowidx >> 9;
    int b = bp >> 4;
    int tid = threadIdx.x;
    float4 vK, vV;
    if (s > t) {
        vK = ((const float4*)Kin)[rowidx * 128 + tid];
        vV = vK;
    } else {
        int ip = it[bp];
        int ip2 = it[b * 16 + ip];
        if (s == t) {
            vK = ((const float4*)kws)[(b * 16 + ip) * 128 + tid];
            vV = ((const float4*)kws)[(b * 16 + ip2) * 128 + tid];
        } else {
            vK = ((const float4*)Kin)[((b * 16 + ip) * 512 + s) * 128 + tid];
            vV = ((const float4*)Kin)[((b * 16 + ip2) * 512 + s) * 128 + tid];
        }
    }
    ((float4*)(out + O7))[rowidx * 128 + tid] = vK;
    ((float4*)(out + O8))[rowidx * 128 + tid] = vV;
}

// ===== misc: r4, eps_z, z-resample, I_new. grid 256, 256 thr =====
__global__ __launch_bounds__(256)
void k_misc(const float* __restrict__ r, const float* __restrict__ epsz,
            const float* __restrict__ zws, const int* __restrict__ Iin,
            const int* __restrict__ it, const int* __restrict__ t_ptr,
            float* __restrict__ out)
{
    int t = *t_ptr;
    int idx = blockIdx.x * 256 + threadIdx.x;
    out[O0 + idx] = r[idx];
    out[O5 + idx] = epsz[idx];
    int row = idx >> 9, d = idx & 511;
    int b = row >> 4;
    int ip = it[row];
    out[O1 + idx] = zws[((b * 16 + ip) << 9) + d];
    int s = d;
    float iv;
    if (s < t)       iv = (float)Iin[((b * 16 + ip) << 9) + s];
    else if (s == t) iv = (float)ip;
    else             iv = (float)Iin[idx];
    out[O10 + idx] = iv;
}

extern "C" void kernel_launch(void* const* d_in, const int* in_sizes, int n_in,
                              void* d_out, int out_size, void* d_ws, size_t ws_size,
                              hipStream_t stream) {
    const float* r      = (const float*)d_in[0];
    const int*   x      = (const int*)d_in[1];
    const float* Kin    = (const float*)d_in[2];
    const float* Vin    = (const float*)d_in[3];
    const int*   Iin    = (const int*)d_in[5];
    const int*   t_ptr  = (const int*)d_in[6];
    const float* eps_q  = (const float*)d_in[7];
    const float* eps_k  = (const float*)d_in[8];
    const float* eps_v  = (const float*)d_in[9];
    const float* eps_z  = (const float*)d_in[10];
    const float* gumbel = (const float*)d_in[11];
    const float* Wq = (const float*)d_in[12]; const float* bq = (const float*)d_in[13];
    const float* Wk = (const float*)d_in[14]; const float* bk = (const float*)d_in[15];
    const float* Wv = (const float*)d_in[16]; const float* bv = (const float*)d_in[17];
    const float* Wo = (const float*)d_in[18]; const float* bo = (const float*)d_in[19];
    const float* ln1_g = (const float*)d_in[20]; const float* ln1_b = (const float*)d_in[21];
    const float* ln3_g = (const float*)d_in[22]; const float* ln3_b = (const float*)d_in[23];
    const float* W1 = (const float*)d_in[24]; const float* b1 = (const float*)d_in[25];
    const float* W2 = (const float*)d_in[26]; const float* b2 = (const float*)d_in[27];
    const float* Wout = (const float*)d_in[28]; const float* bout = (const float*)d_in[29];

    float* ws  = (float*)d_ws;
    float* q   = ws + WQ;
    float* kv  = ws + WK;
    float* vv  = ws + WV;
    float* zp  = ws + WZ;
    float* o1  = ws + WO1;
    float* h1  = ws + WH1;
    float* rr  = ws + WR;
    float* pr  = ws + WPRED;
    float* rmx = ws + WMAX;
    float* rsm = ws + WSUM;
    float* wsq = ws + WWSQ;
    int*   itw = (int*)(ws + WIT);
    int*   amw = (int*)(ws + WAMW);
    float* f2p = ws + WF2P;
    float* scw = ws + WSC;
    float* zpt = ws + WZP;
    float* outp = (float*)d_out;

    k_qkv<<<dim3(4, 16, 3), 512, 0, stream>>>(r, Wq, bq, eps_q, q, Wk, bk, eps_k, kv, Wv, bv, eps_v, vv);
    k_score<<<dim3(128, 4), 512, 0, stream>>>(q, kv, Kin, t_ptr, scw);
    k_smax<<<128, 512, 0, stream>>>(scw, t_ptr, outp);
    k_pv<<<dim3(128, 4), 512, 0, stream>>>(scw, vv, Vin, t_ptr, zpt);
    k_zproj<<<dim3(4, 16), 512, 0, stream>>>(zpt, Wo, bo, eps_z, zp);
    k_ln<<<128, 512, 0, stream>>>(zp, r, ln1_g, ln1_b, o1);
    k_ffn1<<<dim3(16, 8), 512, 0, stream>>>(o1, W1, b1, h1);
    k_ffn2p<<<dim3(4, 8, 4), 512, 0, stream>>>(h1, W2, f2p);
    k_ln_sum4<<<128, 512, 0, stream>>>(f2p, b2, o1, ln3_g, ln3_b, rr);
    k_pred<<<dim3(40, 4), 512, 0, stream>>>(rr, Wout, bout, pr);
    k_soft<<<128, 512, 0, stream>>>(pr, x, rmx, rsm, wsq, outp);
    k_sample<<<1, 128, 0, stream>>>(wsq, gumbel, itw, amw);
    k_vocab<<<dim3(20, 8), 512, 0, stream>>>(pr, rmx, rsm, amw, outp);
    k_resample<<<65536, 128, 0, stream>>>(Kin, kv, itw, t_ptr, outp);
    k_misc<<<256, 256, 0, stream>>>(r, eps_z, zp, Iin, itw, t_ptr, outp);
}

// Round 4
// 273.302 us; speedup vs baseline: 3.2496x; 1.1616x over previous
//
#include <hip/hip_runtime.h>

#define NDFF 2048
#define NVOC 10000
#define SIGMA 0.1f

typedef float f32x4 __attribute__((ext_vector_type(4)));

// ---- output offsets (floats) ----
#define O0 0
#define O1 65536
#define O2 131072
#define O3 211072
#define O4 291072
#define O5 371072
#define O6 436608
#define O7 502144
#define O8 34056576
#define O9 67611008
#define O10 67611136

// ---- workspace offsets (floats) ----
#define WQ    0
#define WK    65536
#define WV    131072
#define WZ    196608
#define WO1   262144
#define WH1   327680
#define WR    589824
#define WPRED 655360
#define WMAX  1935360
#define WSUM  1935488
#define WWSQ  1935616
#define WIT   1935744
#define WAMW  1935872
#define WF2P  1936000   // 4 x 128 x 512
#define WSC   2198144   // 128 x 8 x 512 raw scores
#define WZP   2722432   // 8 x 128 x 512 pv partials

// ===== fused QKV projection: out = r @ W + b + SIGMA*eps =====
// grid (4 coltiles of 128, 16 rowgroups of 8, 3 matrices), 512 thr
__global__ __launch_bounds__(512)
void k_qkv(const float* __restrict__ r,
           const float* __restrict__ Wq, const float* __restrict__ bq, const float* __restrict__ eq, float* __restrict__ oq,
           const float* __restrict__ Wk, const float* __restrict__ bk, const float* __restrict__ ek, float* __restrict__ ok,
           const float* __restrict__ Wv, const float* __restrict__ bv, const float* __restrict__ ev, float* __restrict__ ov)
{
    const float *W, *bias, *eps; float* out;
    if (blockIdx.z == 0)      { W = Wq; bias = bq; eps = eq; out = oq; }
    else if (blockIdx.z == 1) { W = Wk; bias = bk; eps = ek; out = ok; }
    else                      { W = Wv; bias = bv; eps = ev; out = ov; }
    int tid = threadIdx.x;
    int col = tid & 127, kq = tid >> 7;
    int colg = blockIdx.x * 128 + col;
    int row0 = blockIdx.y * 8;
    __shared__ float rs[8][512];
#pragma unroll
    for (int p = 0; p < 8; p++) rs[p][tid & 511] = r[(row0 + p) * 512 + tid];
    __syncthreads();
    float acc[8] = {0,0,0,0,0,0,0,0};
    const float* Wp = W + (kq * 128) * 512 + colg;
#pragma unroll 8
    for (int d = 0; d < 128; d++) {
        float wv = Wp[d * 512];
#pragma unroll
        for (int p = 0; p < 8; p++) acc[p] += rs[p][kq * 128 + d] * wv;
    }
    __syncthreads();
    float (*part)[8][128] = (float(*)[8][128])rs;
#pragma unroll
    for (int p = 0; p < 8; p++) part[kq][p][col] = acc[p];
    __syncthreads();
#pragma unroll
    for (int j = 0; j < 2; j++) {
        int idx = tid + j * 512;
        int p = idx >> 7, c = idx & 127;
        int cg = blockIdx.x * 128 + c;
        float v = part[0][p][c] + part[1][p][c] + part[2][p][c] + part[3][p][c]
                + bias[cg] + SIGMA * eps[(row0 + p) * 512 + cg];
        out[(row0 + p) * 512 + cg] = v;
    }
}

// ===== attention scores (raw): grid (128 bp, 8 schunk), 512 thr =====
__global__ __launch_bounds__(512)
void k_score(const float* __restrict__ qws, const float* __restrict__ kws,
             const float* __restrict__ Kin, const int* __restrict__ t_ptr,
             float* __restrict__ scw)
{
    int t = *t_ptr;
    int bp = blockIdx.x;
    int len = (t + 8) >> 3;
    int lo = blockIdx.y * len;
    int hi = min(lo + len, t + 1);
    int tid = threadIdx.x;
    int wave = tid >> 6, lane = tid & 63;
    const float4* q4 = (const float4*)(qws + bp * 512);
    float4 qa = q4[lane * 2], qb = q4[lane * 2 + 1];
    for (int s = lo + wave; s < hi; s += 8) {
        const float4* kr = (s == t) ? (const float4*)(kws + bp * 512)
                                    : (const float4*)(Kin + (bp * 512 + s) * 512);
        float4 a = kr[lane * 2], c = kr[lane * 2 + 1];
        float partial = qa.x * a.x + qa.y * a.y + qa.z * a.z + qa.w * a.w
                      + qb.x * c.x + qb.y * c.y + qb.z * c.z + qb.w * c.w;
#pragma unroll
        for (int m = 1; m < 8; m <<= 1) partial += __shfl_xor(partial, m, 64);
        if ((lane & 7) == 0) scw[(bp * 8 + (lane >> 3)) * 512 + s] = partial * 0.125f;
    }
}

// ===== PV with fused softmax: grid (128 bp, 8 schunk), 512 thr =====
// scw holds RAW scores; per-head max/sum computed in-block; chunk 0 writes O6.
__global__ __launch_bounds__(512)
void k_pv(const float* __restrict__ scw, const float* __restrict__ vws,
          const float* __restrict__ Vin, const int* __restrict__ t_ptr,
          float* __restrict__ zpart, float* __restrict__ out)
{
    int t = *t_ptr;
    int bp = blockIdx.x;
    int sc = blockIdx.y;
    int len = (t + 8) >> 3;
    int lo = sc * len;
    int hi = min(lo + len, t + 1);
    int tid = threadIdx.x;
    int wave = tid >> 6, lane = tid & 63;
    __shared__ float smh[8], ssh[8];
    __shared__ float sa[8][68];
    // per-head softmax stats (wave = head)
    {
        const float* sp = scw + (bp * 8 + wave) * 512;
        float m = -3.0e38f;
        for (int s = lane; s <= t; s += 64) m = fmaxf(m, sp[s]);
#pragma unroll
        for (int o = 32; o; o >>= 1) m = fmaxf(m, __shfl_xor(m, o, 64));
        float sum = 0.f;
        for (int s = lane; s <= t; s += 64) sum += __expf(sp[s] - m);
#pragma unroll
        for (int o = 32; o; o >>= 1) sum += __shfl_xor(sum, o, 64);
        if (lane == 0) { smh[wave] = m; ssh[wave] = 1.f / sum; }
    }
    __syncthreads();
    // local chunk attn weights
    for (int idx = tid; idx < 8 * len; idx += 512) {
        int hh = idx / len, j = idx - hh * len;
        int s = lo + j;
        sa[hh][j] = (s < hi) ? __expf(scw[(bp * 8 + hh) * 512 + s] - smh[hh]) * ssh[hh] : 0.f;
    }
    __syncthreads();
    int h = tid >> 6;
    float acc = 0.f;
    int hv = min(hi, t);   // rows strictly below t
    int s = lo;
    for (; s + 4 <= hv; s += 4) {
        float v0 = __builtin_nontemporal_load(&Vin[(bp * 512 + s + 0) * 512 + tid]);
        float v1 = __builtin_nontemporal_load(&Vin[(bp * 512 + s + 1) * 512 + tid]);
        float v2 = __builtin_nontemporal_load(&Vin[(bp * 512 + s + 2) * 512 + tid]);
        float v3 = __builtin_nontemporal_load(&Vin[(bp * 512 + s + 3) * 512 + tid]);
        acc += sa[h][s - lo] * v0 + sa[h][s + 1 - lo] * v1
             + sa[h][s + 2 - lo] * v2 + sa[h][s + 3 - lo] * v3;
    }
    for (; s < hv; s++) acc += sa[h][s - lo] * __builtin_nontemporal_load(&Vin[(bp * 512 + s) * 512 + tid]);
    if (t >= lo && t < hi) acc += sa[h][t - lo] * vws[bp * 512 + tid];
    zpart[sc * 65536 + bp * 512 + tid] = acc;
    // attn_weights by chunk 0
    if (sc == 0) {
        int ss = tid;
        float a = 0.f;
        if (ss <= t) {
#pragma unroll
            for (int hh = 0; hh < 8; hh++)
                a += __expf(scw[(bp * 8 + hh) * 512 + ss] - smh[hh]) * ssh[hh];
            a *= 0.125f;
        }
        out[O6 + bp * 512 + ss] = a;
    }
}

// ===== z projection: zh = sum8(zpart), zp = zh @ Wo + bo + SIGMA*eps_z =====
// grid (4 coltiles, 16 rowgroups of 8), 512 thr
__global__ __launch_bounds__(512)
void k_zproj(const float* __restrict__ zpart, const float* __restrict__ Wo,
             const float* __restrict__ bo, const float* __restrict__ epsz,
             float* __restrict__ out)
{
    int tid = threadIdx.x;
    int col = tid & 127, kq = tid >> 7;
    int colg = blockIdx.x * 128 + col;
    int row0 = blockIdx.y * 8;
    __shared__ float rs[8][512];
#pragma unroll
    for (int p = 0; p < 8; p++) {
        int idx = (row0 + p) * 512 + tid;
        float v = 0.f;
#pragma unroll
        for (int j = 0; j < 8; j++) v += zpart[j * 65536 + idx];
        rs[p][tid] = v;
    }
    __syncthreads();
    float acc[8] = {0,0,0,0,0,0,0,0};
    const float* Wp = Wo + (kq * 128) * 512 + colg;
#pragma unroll 8
    for (int d = 0; d < 128; d++) {
        float wv = Wp[d * 512];
#pragma unroll
        for (int p = 0; p < 8; p++) acc[p] += rs[p][kq * 128 + d] * wv;
    }
    __syncthreads();
    float (*part)[8][128] = (float(*)[8][128])rs;
#pragma unroll
    for (int p = 0; p < 8; p++) part[kq][p][col] = acc[p];
    __syncthreads();
#pragma unroll
    for (int j = 0; j < 2; j++) {
        int idx = tid + j * 512;
        int p = idx >> 7, c = idx & 127;
        int cg = blockIdx.x * 128 + c;
        out[(row0 + p) * 512 + cg] = part[0][p][c] + part[1][p][c] + part[2][p][c] + part[3][p][c]
                                   + bo[cg] + SIGMA * epsz[(row0 + p) * 512 + cg];
    }
}

// ===== layernorm: out = LN(a+b)*g + beta. grid 128, 512 thr =====
__global__ __launch_bounds__(512)
void k_ln(const float* __restrict__ a, const float* __restrict__ b,
          const float* __restrict__ g, const float* __restrict__ beta,
          float* __restrict__ out)
{
    __shared__ float red[8];
    int row = blockIdx.x, tid = threadIdx.x;
    float x = a[row * 512 + tid] + b[row * 512 + tid];
    float s = x;
#pragma unroll
    for (int o = 32; o; o >>= 1) s += __shfl_xor(s, o, 64);
    if ((tid & 63) == 0) red[tid >> 6] = s;
    __syncthreads();
    float tot = 0.f;
#pragma unroll
    for (int i = 0; i < 8; i++) tot += red[i];
    float mu = tot * (1.f / 512.f);
    float dx = x - mu;
    float s2 = dx * dx;
#pragma unroll
    for (int o = 32; o; o >>= 1) s2 += __shfl_xor(s2, o, 64);
    __syncthreads();
    if ((tid & 63) == 0) red[tid >> 6] = s2;
    __syncthreads();
    float tot2 = 0.f;
#pragma unroll
    for (int i = 0; i < 8; i++) tot2 += red[i];
    float var = tot2 * (1.f / 512.f);
    out[row * 512 + tid] = dx * rsqrtf(var + 1e-6f) * g[tid] + beta[tid];
}

// ===== ln3 with ffn2-partial reduction: out = LN(sum(f2p)+b2 + o1) =====
__global__ __launch_bounds__(512)
void k_ln_sum4(const float* __restrict__ f2p, const float* __restrict__ b2,
               const float* __restrict__ o1, const float* __restrict__ g,
               const float* __restrict__ beta, float* __restrict__ out)
{
    __shared__ float red[8];
    int row = blockIdx.x, tid = threadIdx.x;
    int idx = row * 512 + tid;
    float x = f2p[idx] + f2p[65536 + idx] + f2p[131072 + idx] + f2p[196608 + idx]
            + b2[tid] + o1[idx];
    float s = x;
#pragma unroll
    for (int o = 32; o; o >>= 1) s += __shfl_xor(s, o, 64);
    if ((tid & 63) == 0) red[tid >> 6] = s;
    __syncthreads();
    float tot = 0.f;
#pragma unroll
    for (int i = 0; i < 8; i++) tot += red[i];
    float mu = tot * (1.f / 512.f);
    float dx = x - mu;
    float s2 = dx * dx;
#pragma unroll
    for (int o = 32; o; o >>= 1) s2 += __shfl_xor(s2, o, 64);
    __syncthreads();
    if ((tid & 63) == 0) red[tid >> 6] = s2;
    __syncthreads();
    float tot2 = 0.f;
#pragma unroll
    for (int i = 0; i < 8; i++) tot2 += red[i];
    float var = tot2 * (1.f / 512.f);
    out[idx] = dx * rsqrtf(var + 1e-6f) * g[tid] + beta[tid];
}

// ===== ffn1: h1 = relu(o1 @ W1 + b1). grid (16 coltiles, 8 rowgroups of 16), 512 thr =====
__global__ __launch_bounds__(512)
void k_ffn1(const float* __restrict__ in, const float* __restrict__ W1,
            const float* __restrict__ b1, float* __restrict__ h1)
{
    int tid = threadIdx.x;
    int col = tid & 127, kq = tid >> 7;
    int colg = blockIdx.x * 128 + col;
    int row0 = blockIdx.y * 16;
    __shared__ float rs[16][512];
#pragma unroll
    for (int j = 0; j < 16; j++) {
        int idx = tid + j * 512;
        rs[idx >> 9][idx & 511] = in[(row0 + (idx >> 9)) * 512 + (idx & 511)];
    }
    __syncthreads();
    float acc[16];
#pragma unroll
    for (int p = 0; p < 16; p++) acc[p] = 0.f;
    const float* Wp = W1 + (kq * 128) * NDFF + colg;
#pragma unroll 8
    for (int d = 0; d < 128; d++) {
        float wv = Wp[d * NDFF];
#pragma unroll
        for (int p = 0; p < 16; p++) acc[p] += rs[p][kq * 128 + d] * wv;
    }
    __syncthreads();
    float (*part)[16][128] = (float(*)[16][128])rs;
#pragma unroll
    for (int p = 0; p < 16; p++) part[kq][p][col] = acc[p];
    __syncthreads();
#pragma unroll
    for (int j = 0; j < 4; j++) {
        int idx = tid + j * 512;
        int p = idx >> 7, c = idx & 127;
        int cg = blockIdx.x * 128 + c;
        float v = part[0][p][c] + part[1][p][c] + part[2][p][c] + part[3][p][c] + b1[cg];
        h1[(row0 + p) * NDFF + cg] = fmaxf(v, 0.f);
    }
}

// ===== ffn2 partials: grid (4 coltiles, 8 rowgroups of 16, 4 ksect of 512), 512 thr =====
__global__ __launch_bounds__(512)
void k_ffn2p(const float* __restrict__ h1, const float* __restrict__ W2,
             float* __restrict__ f2p)
{
    int tid = threadIdx.x;
    int col = tid & 127, kq = tid >> 7;
    int colg = blockIdx.x * 128 + col;
    int row0 = blockIdx.y * 16;
    int ks = blockIdx.z;
    __shared__ float rs[16][512];
#pragma unroll
    for (int j = 0; j < 16; j++) {
        int idx = tid + j * 512;
        rs[idx >> 9][idx & 511] = h1[(row0 + (idx >> 9)) * NDFF + ks * 512 + (idx & 511)];
    }
    __syncthreads();
    float acc[16];
#pragma unroll
    for (int p = 0; p < 16; p++) acc[p] = 0.f;
    const float* Wp = W2 + (ks * 512 + kq * 128) * 512 + colg;
#pragma unroll 8
    for (int d = 0; d < 128; d++) {
        float wv = Wp[d * 512];
#pragma unroll
        for (int p = 0; p < 16; p++) acc[p] += rs[p][kq * 128 + d] * wv;
    }
    __syncthreads();
    float (*part)[16][128] = (float(*)[16][128])rs;
#pragma unroll
    for (int p = 0; p < 16; p++) part[kq][p][col] = acc[p];
    __syncthreads();
#pragma unroll
    for (int j = 0; j < 4; j++) {
        int idx = tid + j * 512;
        int p = idx >> 7, c = idx & 127;
        int cg = blockIdx.x * 128 + c;
        f2p[ks * 65536 + (row0 + p) * 512 + cg] =
            part[0][p][c] + part[1][p][c] + part[2][p][c] + part[3][p][c];
    }
}

// ===== pred = r_ @ Wout + bout. grid (40 coltiles of 256, 4 rowgroups of 32), 512 thr =====
__global__ __launch_bounds__(512)
void k_pred(const float* __restrict__ r_, const float* __restrict__ Wout,
            const float* __restrict__ bout, float* __restrict__ pred)
{
    int tid = threadIdx.x;
    int col = tid & 255, kh = tid >> 8;
    int colg = blockIdx.x * 256 + col;
    int colL = min(colg, NVOC - 1);
    int row0 = blockIdx.y * 32;
    __shared__ float rs[32][256];
    float acc[32];
#pragma unroll
    for (int p = 0; p < 32; p++) acc[p] = 0.f;
    for (int kc = 0; kc < 2; kc++) {
        __syncthreads();
#pragma unroll
        for (int j = 0; j < 16; j++) {
            int idx = tid + j * 512;
            rs[idx >> 8][idx & 255] = r_[(row0 + (idx >> 8)) * 512 + kc * 256 + (idx & 255)];
        }
        __syncthreads();
        const float* Wp = Wout + (kc * 256 + kh * 128) * NVOC + colL;
#pragma unroll 4
        for (int d = 0; d < 128; d++) {
            float wv = Wp[d * NVOC];
#pragma unroll
            for (int p = 0; p < 32; p++) acc[p] += rs[p][kh * 128 + d] * wv;
        }
    }
    __syncthreads();
    float (*part)[256] = (float(*)[256])rs;
    if (kh == 1) {
#pragma unroll
        for (int p = 0; p < 32; p++) part[p][col] = acc[p];
    }
    __syncthreads();
    if (kh == 0 && colg < NVOC) {
        float bv = bout[colg];
#pragma unroll
        for (int p = 0; p < 32; p++)
            pred[(row0 + p) * NVOC + colg] = acc[p] + part[p][col] + bv;
    }
}

// ===== per-row softmax stats + w_sq. grid 128, 512 thr =====
__global__ __launch_bounds__(512)
void k_soft(const float* __restrict__ pred, const int* __restrict__ x,
            float* __restrict__ rowmax, float* __restrict__ rowsum,
            float* __restrict__ wsq, float* __restrict__ out)
{
    __shared__ float red[8];
    int row = blockIdx.x, tid = threadIdx.x;
    const float* pr = pred + row * NVOC;
    float m = -3.0e38f;
    for (int v = tid; v < NVOC; v += 512) m = fmaxf(m, pr[v]);
#pragma unroll
    for (int o = 32; o; o >>= 1) m = fmaxf(m, __shfl_xor(m, o, 64));
    if ((tid & 63) == 0) red[tid >> 6] = m;
    __syncthreads();
#pragma unroll
    for (int i = 0; i < 8; i++) m = fmaxf(m, red[i]);
    __syncthreads();
    float s = 0.f;
    for (int v = tid; v < NVOC; v += 512) s += __expf(pr[v] - m);
#pragma unroll
    for (int o = 32; o; o >>= 1) s += __shfl_xor(s, o, 64);
    if ((tid & 63) == 0) red[tid >> 6] = s;
    __syncthreads();
    if (tid == 0) {
        float tot = 0.f;
#pragma unroll
        for (int i = 0; i < 8; i++) tot += red[i];
        rowmax[row] = m; rowsum[row] = tot;
        int b = row >> 4;
        float w = __expf(pr[x[b]] - m) / tot;
        wsq[row] = w;
        out[O9 + row] = w;
    }
}

// ===== gumbel argmax + argmax_w. 1 block, 128 thr =====
__global__ __launch_bounds__(128)
void k_sample(const float* __restrict__ wsq, const float* __restrict__ gumbel,
              int* __restrict__ it, int* __restrict__ amw)
{
    int tid = threadIdx.x;
    int b = tid >> 4, p = tid & 15;
    float best = -3.0e38f; int bi = 0;
#pragma unroll
    for (int pp = 0; pp < 16; pp++) {
        float v = logf(wsq[b * 16 + pp] + 1e-10f) + gumbel[tid * 16 + pp];
        if (v > best) { best = v; bi = pp; }
    }
    it[tid] = bi;
    if (p == 0) {
        float bw = -3.0e38f; int bj = 0;
#pragma unroll
        for (int pp = 0; pp < 16; pp++) {
            float wv = wsq[b * 16 + pp];
            if (wv > bw) { bw = wv; bj = pp; }
        }
        amw[b] = bj;
    }
}

// ===== vocab outputs. grid (20, 8), 512 thr =====
__global__ __launch_bounds__(512)
void k_vocab(const float* __restrict__ pred, const float* __restrict__ rowmax,
             const float* __restrict__ rowsum, const int* __restrict__ amw,
             float* __restrict__ out)
{
    int v = blockIdx.x * 512 + threadIdx.x;
    if (v >= NVOC) return;
    int b = blockIdx.y;
    float ga = 0.f, as = 0.f;
#pragma unroll
    for (int p = 0; p < 16; p++) {
        int rr = b * 16 + p;
        float pv = pred[rr * NVOC + v];
        ga += pv;
        as += __expf(pv - rowmax[rr]) * (1.f / rowsum[rr]);
    }
    out[O3 + b * NVOC + v] = ga * (1.f / 16.f);
    out[O2 + b * NVOC + v] = as * (1.f / 16.f);
    out[O4 + b * NVOC + v] = pred[(b * 16 + amw[b]) * NVOC + v];
}

// ===== K / Vs resample: grid-stride, NT loads for s>t stream, NT stores =====
// 4096 blocks x 256 thr; i indexes float4 units of the (8,16,512,512) layout.
__global__ __launch_bounds__(256)
void k_resample(const float* __restrict__ Kin, const float* __restrict__ kws,
                const int* __restrict__ it, const int* __restrict__ t_ptr,
                float* __restrict__ out)
{
    int t = *t_ptr;
    const f32x4* K4  = (const f32x4*)Kin;
    const f32x4* kw4 = (const f32x4*)kws;
    f32x4* oK = (f32x4*)(out + O7);
    f32x4* oV = (f32x4*)(out + O8);
    const int total = 128 * 512 * 128;
    for (int i = blockIdx.x * 256 + threadIdx.x; i < total; i += gridDim.x * 256) {
        int lane = i & 127;
        int row = i >> 7;
        int s = row & 511;
        int bp = row >> 9;
        int b = bp >> 4;
        f32x4 vK, vV;
        if (s > t) {
            vK = __builtin_nontemporal_load(&K4[i]);
            vV = vK;
        } else {
            int ip = it[bp];
            int ip2 = it[b * 16 + ip];
            if (s == t) {
                vK = kw4[(b * 16 + ip) * 128 + lane];
                vV = kw4[(b * 16 + ip2) * 128 + lane];
            } else {
                vK = K4[((b * 16 + ip) * 512 + s) * 128 + lane];
                vV = K4[((b * 16 + ip2) * 512 + s) * 128 + lane];
            }
        }
        __builtin_nontemporal_store(vK, &oK[i]);
        __builtin_nontemporal_store(vV, &oV[i]);
    }
}

// ===== misc: r4, eps_z, z-resample, I_new. grid 256, 256 thr =====
__global__ __launch_bounds__(256)
void k_misc(const float* __restrict__ r, const float* __restrict__ epsz,
            const float* __restrict__ zws, const int* __restrict__ Iin,
            const int* __restrict__ it, const int* __restrict__ t_ptr,
            float* __restrict__ out)
{
    int t = *t_ptr;
    int idx = blockIdx.x * 256 + threadIdx.x;
    out[O0 + idx] = r[idx];
    out[O5 + idx] = epsz[idx];
    int row = idx >> 9, d = idx & 511;
    int b = row >> 4;
    int ip = it[row];
    out[O1 + idx] = zws[((b * 16 + ip) << 9) + d];
    int s = d;
    float iv;
    if (s < t)       iv = (float)Iin[((b * 16 + ip) << 9) + s];
    else if (s == t) iv = (float)ip;
    else             iv = (float)Iin[idx];
    out[O10 + idx] = iv;
}

extern "C" void kernel_launch(void* const* d_in, const int* in_sizes, int n_in,
                              void* d_out, int out_size, void* d_ws, size_t ws_size,
                              hipStream_t stream) {
    const float* r      = (const float*)d_in[0];
    const int*   x      = (const int*)d_in[1];
    const float* Kin    = (const float*)d_in[2];
    const float* Vin    = (const float*)d_in[3];
    const int*   Iin    = (const int*)d_in[5];
    const int*   t_ptr  = (const int*)d_in[6];
    const float* eps_q  = (const float*)d_in[7];
    const float* eps_k  = (const float*)d_in[8];
    const float* eps_v  = (const float*)d_in[9];
    const float* eps_z  = (const float*)d_in[10];
    const float* gumbel = (const float*)d_in[11];
    const float* Wq = (const float*)d_in[12]; const float* bq = (const float*)d_in[13];
    const float* Wk = (const float*)d_in[14]; const float* bk = (const float*)d_in[15];
    const float* Wv = (const float*)d_in[16]; const float* bv = (const float*)d_in[17];
    const float* Wo = (const float*)d_in[18]; const float* bo = (const float*)d_in[19];
    const float* ln1_g = (const float*)d_in[20]; const float* ln1_b = (const float*)d_in[21];
    const float* ln3_g = (const float*)d_in[22]; const float* ln3_b = (const float*)d_in[23];
    const float* W1 = (const float*)d_in[24]; const float* b1 = (const float*)d_in[25];
    const float* W2 = (const float*)d_in[26]; const float* b2 = (const float*)d_in[27];
    const float* Wout = (const float*)d_in[28]; const float* bout = (const float*)d_in[29];

    float* ws  = (float*)d_ws;
    float* q   = ws + WQ;
    float* kv  = ws + WK;
    float* vv  = ws + WV;
    float* zp  = ws + WZ;
    float* o1  = ws + WO1;
    float* h1  = ws + WH1;
    float* rr  = ws + WR;
    float* pr  = ws + WPRED;
    float* rmx = ws + WMAX;
    float* rsm = ws + WSUM;
    float* wsq = ws + WWSQ;
    int*   itw = (int*)(ws + WIT);
    int*   amw = (int*)(ws + WAMW);
    float* f2p = ws + WF2P;
    float* scw = ws + WSC;
    float* zpt = ws + WZP;
    float* outp = (float*)d_out;

    k_qkv<<<dim3(4, 16, 3), 512, 0, stream>>>(r, Wq, bq, eps_q, q, Wk, bk, eps_k, kv, Wv, bv, eps_v, vv);
    k_score<<<dim3(128, 8), 512, 0, stream>>>(q, kv, Kin, t_ptr, scw);
    k_pv<<<dim3(128, 8), 512, 0, stream>>>(scw, vv, Vin, t_ptr, zpt, outp);
    k_zproj<<<dim3(4, 16), 512, 0, stream>>>(zpt, Wo, bo, eps_z, zp);
    k_ln<<<128, 512, 0, stream>>>(zp, r, ln1_g, ln1_b, o1);
    k_ffn1<<<dim3(16, 8), 512, 0, stream>>>(o1, W1, b1, h1);
    k_ffn2p<<<dim3(4, 8, 4), 512, 0, stream>>>(h1, W2, f2p);
    k_ln_sum4<<<128, 512, 0, stream>>>(f2p, b2, o1, ln3_g, ln3_b, rr);
    k_pred<<<dim3(40, 4), 512, 0, stream>>>(rr, Wout, bout, pr);
    k_soft<<<128, 512, 0, stream>>>(pr, x, rmx, rsm, wsq, outp);
    k_sample<<<1, 128, 0, stream>>>(wsq, gumbel, itw, amw);
    k_vocab<<<dim3(20, 8), 512, 0, stream>>>(pr, rmx, rsm, amw, outp);
    k_resample<<<4096, 256, 0, stream>>>(Kin, kv, itw, t_ptr, outp);
    k_misc<<<256, 256, 0, stream>>>(r, eps_z, zp, Iin, itw, t_ptr, outp);
}